// Round 5
// baseline (181.622 us; speedup 1.0000x reference)
//
#include <hip/hip_runtime.h>

#define N_SAMPLES 131072
#define N_EVENTS 128
#define N_ATOMS 32
#define ATOM_SIZE 512
#define LATENT 16
#define TIME_DIM 17
#define LAYERS 7
#define TDIM2 (2 * TIME_DIM)   // 34

// dot of a 16-element f32 row (16B-aligned, global) with 16 floats in LDS
__device__ __forceinline__ float dot16f(const float* __restrict__ wr,
                                        const float* __restrict__ x) {
    const float4* q = (const float4*)wr;
    float4 a = q[0], b = q[1], c = q[2], d = q[3];
    float s = 0.f;
    s += a.x * x[0]  + a.y * x[1]  + a.z * x[2]  + a.w * x[3];
    s += b.x * x[4]  + b.y * x[5]  + b.z * x[6]  + b.w * x[7];
    s += c.x * x[8]  + c.y * x[9]  + c.z * x[10] + c.w * x[11];
    s += d.x * x[12] + d.y * x[13] + d.z * x[14] + d.w * x[15];
    return s;
}

// Single-dispatch gather-owner kernel. 512 blocks x 256 threads; block b owns
// out[b*256, b*256+256) and writes it exactly once (no memset, no atomics,
// no workspace, no grid barrier — R3 showed device-scope fencing costs ~70us).
// Each block redundantly walks the FULL 7-layer binary tree breadth-first in
// LDS (254 nodes x 50 dots ~= 203K FMA, ~free), derives all 128 event
// positions/amps/atom-coeffs, then gathers the <=~1 events overlapping its
// range, recomputing atom samples (32 FMA/sample) for norm and output.
__global__ __launch_bounds__(256) void fused_gather_kernel(
    const float* __restrict__ base_latent,
    const float* __restrict__ to_time_W,
    const float* __restrict__ split_W,
    const float* __restrict__ split_b,
    const float* __restrict__ atoms,
    const float* __restrict__ to_atoms_W,
    const float* __restrict__ to_atoms_b,
    const float* __restrict__ to_amp_W,
    const float* __restrict__ to_amp_b,
    float* __restrict__ out)   // [131072]
{
    const int t = threadIdx.x;
    const int k0 = blockIdx.x * 256;

    __shared__ float sx[2][N_EVENTS * LATENT];   // 2 x 8 KB   x per node
    __shared__ float st[2][N_EVENTS * TDIM2];    // 2 x 17 KB  times per node
    __shared__ int   sp[N_EVENTS];
    __shared__ float samp[N_EVENTS];
    __shared__ int   ev_e[N_EVENTS];
    __shared__ int   ev_p[N_EVENTS];
    __shared__ float ev_s[N_EVENTS];
    __shared__ float wred[4];
    __shared__ int   cnt;
    // a32[128][32] overlaid on st[0] (dead after the walk: leaves are in [1])
    float* a32 = st[0];

    // ---- init root (node 0 in buffers [0]) ----
    if (t < LATENT) sx[0][t] = base_latent[t];
    else if (t < LATENT + TDIM2) st[0][t - LATENT] = 0.f;
    if (t == 0) cnt = 0;
    __syncthreads();

    // ---- breadth-first tree walk: layer i reads [i&1], writes [(i+1)&1] ----
    for (int i = 0; i < LAYERS; ++i) {
        const float* xprev = sx[i & 1];
        float*       xnext = sx[(i + 1) & 1];
        const float* tprev = st[i & 1];
        float*       tnext = st[(i + 1) & 1];
        const int C = 2 << i;              // children this layer
        const int rows = C * (LATENT + TDIM2);   // C * 50
        for (int r = t; r < rows; r += 256) {
            const int n  = r / 50;
            const int q  = r - n * 50;
            const int par = n >> 1, cb = n & 1;
            const float* xp = xprev + par * LATENT;
            if (q < LATENT) {
                xnext[n * LATENT + q] =
                    split_b[i * 32 + cb * LATENT + q] +
                    dot16f(split_W + (i * 32 + cb * LATENT + q) * LATENT, xp);
            } else {
                const int m = q - LATENT;          // m = 2*d + j
                tnext[n * TDIM2 + m] =
                    tprev[par * TDIM2 + m] +
                    dot16f(to_time_W + (i * 68 + cb * TDIM2 + m) * LATENT, xp);
            }
        }
        __syncthreads();
    }
    // leaves: x in sx[1], times in st[1]  (LAYERS odd)

    // ---- per-event position + amplitude ----
    if (t < N_EVENTS) {
        const float* te = st[1] + t * TDIM2;
        int p = 0;
#pragma unroll
        for (int d = 0; d < TIME_DIM; ++d) {
            if (te[2 * d + 1] > te[2 * d]) p |= 1 << (16 - d);
        }
        sp[t] = p;
        samp[t] = to_amp_b[0] + dot16f(to_amp_W, sx[1] + t * LATENT);
    }
    // ---- atom coefficients for all events (4096 dots) ----
    for (int r = t; r < N_EVENTS * N_ATOMS; r += 256) {
        const int e = r >> 5, m = r & 31;
        a32[e * N_ATOMS + m] =
            to_atoms_b[m] + dot16f(to_atoms_W + m * LATENT, sx[1] + e * LATENT);
    }
    __syncthreads();

    // ---- overlap list: events with segment [p, p+512) meeting [k0, k0+256) ----
    if (t < N_EVENTS) {
        const int p = sp[t];
        if (p + ATOM_SIZE > k0 && p < k0 + 256) {
            const int idx = atomicAdd(&cnt, 1);
            ev_e[idx] = t;
            ev_p[idx] = p;
        }
    }
    __syncthreads();
    const int n = cnt;

    // ---- norms (recompute atom) for listed events only ----
    for (int i = 0; i < n; ++i) {
        const float* ae = a32 + ev_e[i] * N_ATOMS;
        float acc0 = 0.f, acc1 = 0.f;
#pragma unroll
        for (int m = 0; m < N_ATOMS; ++m) {
            acc0 += ae[m] * atoms[m * ATOM_SIZE + t];
            acc1 += ae[m] * atoms[m * ATOM_SIZE + 256 + t];
        }
        const float w0 = 0.54f - 0.46f * cosf((float)t * (float)(M_PI / 256.0));
        const float w1 =
            0.54f - 0.46f * cosf((float)(t + 256) * (float)(M_PI / 256.0));
        const float v0 = w0 * acc0, v1 = w1 * acc1;
        float ss = v0 * v0 + v1 * v1;
#pragma unroll
        for (int off = 32; off > 0; off >>= 1) ss += __shfl_xor(ss, off, 64);
        if ((t & 63) == 0) wred[t >> 6] = ss;
        __syncthreads();
        if (t == 0) {
            const float tot = wred[0] + wred[1] + wred[2] + wred[3];
            ev_s[i] = samp[ev_e[i]] / (sqrtf(tot) + 1e-8f);
        }
        __syncthreads();
    }

    // ---- produce owned output range (one store per sample) ----
    const int k = k0 + t;
    float sum = 0.f;
    for (int i = 0; i < n; ++i) {
        const unsigned d = (unsigned)(k - ev_p[i]);
        if (d < (unsigned)ATOM_SIZE) {
            const float* ae = a32 + ev_e[i] * N_ATOMS;
            float acc = 0.f;
#pragma unroll
            for (int m = 0; m < N_ATOMS; ++m) acc += ae[m] * atoms[m * ATOM_SIZE + d];
            const float wnd =
                0.54f - 0.46f * cosf((float)d * (float)(M_PI / 256.0));
            sum += wnd * acc * ev_s[i];
        }
    }
    out[k] = sum;
}

extern "C" void kernel_launch(void* const* d_in, const int* in_sizes, int n_in,
                              void* d_out, int out_size, void* d_ws, size_t ws_size,
                              hipStream_t stream)
{
    const float* base_latent = (const float*)d_in[0];
    const float* to_time_W   = (const float*)d_in[1];
    const float* split_W     = (const float*)d_in[2];
    const float* split_b     = (const float*)d_in[3];
    const float* atoms       = (const float*)d_in[4];
    const float* to_atoms_W  = (const float*)d_in[5];
    const float* to_atoms_b  = (const float*)d_in[6];
    const float* to_amp_W    = (const float*)d_in[7];
    const float* to_amp_b    = (const float*)d_in[8];

    fused_gather_kernel<<<N_SAMPLES / 256, 256, 0, stream>>>(
        base_latent, to_time_W, split_W, split_b, atoms,
        to_atoms_W, to_atoms_b, to_amp_W, to_amp_b, (float*)d_out);
}

// Round 6
// 80.332 us; speedup vs baseline: 2.2609x; 2.2609x over previous
//
#include <hip/hip_runtime.h>

#define N_SAMPLES 131072
#define N_EVENTS 128
#define N_ATOMS 32
#define ATOM_SIZE 512
#define LATENT 16
#define TIME_DIM 17
#define LAYERS 7

// dot of a 16-element f32 row with 16 floats in LDS
__device__ __forceinline__ float dot16f(const float* __restrict__ wr,
                                        const float* __restrict__ x) {
    const float4* q = (const float4*)wr;
    float4 a = q[0], b = q[1], c = q[2], d = q[3];
    float s = 0.f;
    s += a.x * x[0]  + a.y * x[1]  + a.z * x[2]  + a.w * x[3];
    s += b.x * x[4]  + b.y * x[5]  + b.z * x[6]  + b.w * x[7];
    s += c.x * x[8]  + c.y * x[9]  + c.z * x[10] + c.w * x[11];
    s += d.x * x[12] + d.y * x[13] + d.z * x[14] + d.w * x[15];
    return s;
}

// R4 structure (best measured: 80.1us total; kernel itself below top-5).
// One block per event (128 blocks x 256 threads). Walks the 7-layer binary
// tree path for event b (child bit c_i = (b>>(6-i))&1), accumulates time
// offsets, computes the hierarchical-dirac position p_b, atom coefficients,
// the windowed + L2-normalized + amp-scaled 512-sample atom, and scatters it
// into out[p_b .. p_b+512) with atomicAdd (out pre-zeroed by memset).
// Measured dead ends: R3 grid-barrier fusion (+55us: device-scope fencing on
// 8 XCDs), R5 512x-redundant tree recompute (+101us: L2-latency-bound).
__global__ __launch_bounds__(256) void expand_scatter_kernel(
    const float* __restrict__ base_latent,
    const float* __restrict__ to_time_W,
    const float* __restrict__ split_W,
    const float* __restrict__ split_b,
    const float* __restrict__ atoms,
    const float* __restrict__ to_atoms_W,
    const float* __restrict__ to_atoms_b,
    const float* __restrict__ to_amp_W,
    const float* __restrict__ to_amp_b,
    float* __restrict__ out)   // [131072], pre-zeroed
{
    const int b = blockIdx.x;
    const int t = threadIdx.x;

    __shared__ float x_cur[LATENT];
    __shared__ float x_next[LATENT];
    __shared__ float times[2 * TIME_DIM];
    __shared__ float a32[N_ATOMS];
    __shared__ float s_amp, s_scale;
    __shared__ float wred[4];
    __shared__ int s_p;

    if (t < LATENT) x_cur[t] = base_latent[t];
    if (t < 2 * TIME_DIM) times[t] = 0.f;
    __syncthreads();

    // --- 7-layer tree walk (50 parallel 16-dots per layer) ---
    for (int i = 0; i < LAYERS; ++i) {
        const int c = (b >> (6 - i)) & 1;
        if (t < LATENT) {
            const int row = c * LATENT + t;
            x_next[t] = split_b[i * 32 + row] +
                        dot16f(split_W + (i * 32 + row) * LATENT, x_cur);
        } else if (t < LATENT + 2 * TIME_DIM) {
            const int m = t - LATENT;                  // m = 2*d + j
            const int row = c * (2 * TIME_DIM) + m;
            times[m] += dot16f(to_time_W + (i * 68 + row) * LATENT, x_cur);
        }
        __syncthreads();
        if (t < LATENT) x_cur[t] = x_next[t];
        __syncthreads();
    }

    // --- dirac position p_b and amplitude ---
    if (t == 0) {
        int p = 0;
#pragma unroll
        for (int d = 0; d < TIME_DIM; ++d) {
            if (times[2 * d + 1] > times[2 * d]) p |= 1 << (16 - d);
        }
        s_p = p;
        s_amp = to_amp_b[0] + dot16f(to_amp_W, x_cur);
    }
    // --- atom coefficients ---
    if (t < N_ATOMS) {
        a32[t] = to_atoms_b[t] + dot16f(to_atoms_W + t * LATENT, x_cur);
    }
    __syncthreads();

    // --- windowed atom: 2 columns per thread (cols t and t+256) ---
    float v0, v1, ss = 0.f;
    {
        float acc = 0.f;
#pragma unroll
        for (int m = 0; m < N_ATOMS; ++m) acc += a32[m] * atoms[m * ATOM_SIZE + t];
        float wnd = 0.54f - 0.46f * cosf((float)t * (float)(M_PI / 256.0));
        v0 = wnd * acc;
        ss += v0 * v0;

        acc = 0.f;
#pragma unroll
        for (int m = 0; m < N_ATOMS; ++m)
            acc += a32[m] * atoms[m * ATOM_SIZE + 256 + t];
        wnd = 0.54f - 0.46f * cosf((float)(t + 256) * (float)(M_PI / 256.0));
        v1 = wnd * acc;
        ss += v1 * v1;
    }
    // block reduce of sum-of-squares (4 waves)
#pragma unroll
    for (int off = 32; off > 0; off >>= 1) ss += __shfl_xor(ss, off, 64);
    if ((t & 63) == 0) wred[t >> 6] = ss;
    __syncthreads();
    if (t == 0) {
        const float tot = wred[0] + wred[1] + wred[2] + wred[3];
        s_scale = s_amp / (sqrtf(tot) + 1e-8f);
    }
    __syncthreads();

    // --- scatter into out[p .. p+512), clipped to N_SAMPLES ---
    const int p = s_p;
    const float scale = s_scale;
    const int k0 = p + t;
    const int k1 = p + 256 + t;
    if (k0 < N_SAMPLES) atomicAdd(out + k0, v0 * scale);
    if (k1 < N_SAMPLES) atomicAdd(out + k1, v1 * scale);
}

extern "C" void kernel_launch(void* const* d_in, const int* in_sizes, int n_in,
                              void* d_out, int out_size, void* d_ws, size_t ws_size,
                              hipStream_t stream)
{
    const float* base_latent = (const float*)d_in[0];
    const float* to_time_W   = (const float*)d_in[1];
    const float* split_W     = (const float*)d_in[2];
    const float* split_b     = (const float*)d_in[3];
    const float* atoms       = (const float*)d_in[4];
    const float* to_atoms_W  = (const float*)d_in[5];
    const float* to_atoms_b  = (const float*)d_in[6];
    const float* to_amp_W    = (const float*)d_in[7];
    const float* to_amp_b    = (const float*)d_in[8];

    // d_out is poisoned 0xAA before every launch — zero it, then scatter-add.
    hipMemsetAsync(d_out, 0, (size_t)out_size * sizeof(float), stream);

    expand_scatter_kernel<<<N_EVENTS, 256, 0, stream>>>(
        base_latent, to_time_W, split_W, split_b, atoms,
        to_atoms_W, to_atoms_b, to_amp_W, to_amp_b, (float*)d_out);
}